// Round 4
// baseline (615.437 us; speedup 1.0000x reference)
//
#include <hip/hip_runtime.h>
#include <math.h>

// ---------------------------------------------------------------------------
// VideoChat3 vision encoder block, bf16-MFMA pipeline. Round 4:
//  - split-K x2 with fp32 atomicAdd epilogue for WO and FC1 (both had
//    512-block grids = 2 blocks/CU, occupancy-starved at 20%)
//  - out pre-seeded with x via hipMemcpyAsync (residual base)
// S=8192, H=1024, NH=16, HD=64, NSEG=8, L=1024, MLP=4096.
// ---------------------------------------------------------------------------

typedef __bf16 bf16x8 __attribute__((ext_vector_type(8)));
typedef float f32x4 __attribute__((ext_vector_type(4)));
typedef float f32x16 __attribute__((ext_vector_type(16)));
typedef unsigned int u32;

__device__ __forceinline__ unsigned short f2b(float f) {  // RNE f32->bf16
  unsigned u = __float_as_uint(f);
  return (unsigned short)((u + 0x7FFFu + ((u >> 16) & 1u)) >> 16);
}
__device__ __forceinline__ float b2f(unsigned short h) {
  return __uint_as_float(((unsigned)h) << 16);
}
__device__ __forceinline__ void async_ld16(const void* g, void* l) {
  __builtin_amdgcn_global_load_lds((__attribute__((address_space(1))) void*)g,
                                   (__attribute__((address_space(3))) void*)l,
                                   16, 0, 0);
}
__device__ __forceinline__ float exp2fast(float x) {
#if __has_builtin(__builtin_amdgcn_exp2f)
  return __builtin_amdgcn_exp2f(x);
#else
  return exp2f(x);
#endif
}
__device__ __forceinline__ float rcpfast(float x) {
#if __has_builtin(__builtin_amdgcn_rcpf)
  return __builtin_amdgcn_rcpf(x);
#else
  return 1.0f / x;
#endif
}

// ---------------- fused weight cast fp32 -> bf16 ---------------------------
__global__ __launch_bounds__(256) void castall_kernel(
    const float* __restrict__ s0, const float* __restrict__ s1,
    const float* __restrict__ s2, const float* __restrict__ s3,
    unsigned short* __restrict__ dst) {
  const int t = blockIdx.x * 256 + threadIdx.x;  // 0..3145727 float4 groups
  const float* src;
  int off;
  if (t < 786432) { src = s0; off = t; }
  else if (t < 1048576) { src = s1; off = t - 786432; }
  else if (t < 2097152) { src = s2; off = t - 1048576; }
  else { src = s3; off = t - 2097152; }
  const float4 v = ((const float4*)src)[off];
  ushort4 o;
  o.x = f2b(v.x); o.y = f2b(v.y); o.z = f2b(v.z); o.w = f2b(v.w);
  ((ushort4*)dst)[t] = o;
}

// ---------------- layernorm (row of 1024) -> bf16 --------------------------
__global__ __launch_bounds__(256) void ln_kernel(const float* __restrict__ x,
                                                 const float* __restrict__ g,
                                                 const float* __restrict__ bt,
                                                 unsigned short* __restrict__ out) {
  __shared__ float red[8];
  const int row = blockIdx.x, t = threadIdx.x;
  const float4 v = ((const float4*)(x + (size_t)row * 1024))[t];
  float s = v.x + v.y + v.z + v.w;
  float s2 = v.x * v.x + v.y * v.y + v.z * v.z + v.w * v.w;
#pragma unroll
  for (int m = 1; m < 64; m <<= 1) {
    s += __shfl_xor(s, m, 64);
    s2 += __shfl_xor(s2, m, 64);
  }
  if ((t & 63) == 0) { red[t >> 6] = s; red[4 + (t >> 6)] = s2; }
  __syncthreads();
  const float ts = red[0] + red[1] + red[2] + red[3];
  const float ts2 = red[4] + red[5] + red[6] + red[7];
  const float mean = ts * (1.f / 1024.f);
  const float var = ts2 * (1.f / 1024.f) - mean * mean;
  const float inv = rsqrtf(var + 1e-5f);
  const float4 gv = ((const float4*)g)[t];
  const float4 bv = ((const float4*)bt)[t];
  ushort4 o;
  o.x = f2b((v.x - mean) * inv * gv.x + bv.x);
  o.y = f2b((v.y - mean) * inv * gv.y + bv.y);
  o.z = f2b((v.z - mean) * inv * gv.z + bv.z);
  o.w = f2b((v.w - mean) * inv * gv.w + bv.w);
  ((ushort4*)out)[(size_t)row * 256 + t] = o;
}

// ---------------- GEMM: C[M,N] = A[M,K] @ B[N,K]^T, bf16 in, fp32 acc ------
// 128x128 tile, 4 waves, 16x16x32 MFMA, XOR-swizzled LDS (conflict-free).
// Split-K via blockIdx.z (Kper = K / gridDim.z).
// MODE 2: outb = bf16(gelu(acc + bias))
// MODE 4: outb = bf16(acc)
// MODE 5: atomicAdd(outf, acc [+ bias if z==0 && bias])  -- split-K epilogue
template <int MODE>
__global__ __launch_bounds__(256) void gemm_bt(
    const unsigned short* __restrict__ A, const unsigned short* __restrict__ B,
    int M, int N, int K, float* __restrict__ outf, unsigned short* __restrict__ outb,
    const float* __restrict__ bias) {
  __shared__ __align__(16) unsigned short As[128 * 32];
  __shared__ __align__(16) unsigned short Bs[128 * 32];
  const int bm = blockIdx.y * 128, bn = blockIdx.x * 128;
  const int Kper = K / gridDim.z;
  const int kbeg = blockIdx.z * Kper, kend = kbeg + Kper;
  const int t = threadIdx.x, wave = t >> 6, lane = t & 63;
  const int quad = lane >> 4, l16 = lane & 15;
  const int wm = (wave >> 1) * 64, wn = (wave & 1) * 64;
  const int srow = lane >> 2;
  const int scol = (((lane & 3) ^ ((lane >> 3) & 3)) * 8);  // swizzled source col
  const unsigned short* Ag0 = A + (size_t)(bm + wave * 32 + srow) * K + scol;
  const unsigned short* Ag1 = Ag0 + (size_t)16 * K;
  const unsigned short* Bg0 = B + (size_t)(bn + wave * 32 + srow) * K + scol;
  const unsigned short* Bg1 = Bg0 + (size_t)16 * K;
  unsigned short* Al = As + wave * 1024;
  unsigned short* Bl = Bs + wave * 1024;
  const int swg = (l16 >> 1) & 3;  // read-side swizzle key
  f32x4 acc[4][4] = {};
  for (int k0 = kbeg; k0 < kend; k0 += 32) {
    async_ld16(Ag0 + k0, Al);
    async_ld16(Ag1 + k0, Al + 512);
    async_ld16(Bg0 + k0, Bl);
    async_ld16(Bg1 + k0, Bl + 512);
    __syncthreads();
    bf16x8 af[4], bfv[4];
#pragma unroll
    for (int i = 0; i < 4; i++)
      af[i] = *(const bf16x8*)(As + (wm + i * 16 + l16) * 32 + (quad ^ swg) * 8);
#pragma unroll
    for (int j = 0; j < 4; j++)
      bfv[j] = *(const bf16x8*)(Bs + (wn + j * 16 + l16) * 32 + (quad ^ swg) * 8);
#pragma unroll
    for (int i = 0; i < 4; i++)
#pragma unroll
      for (int j = 0; j < 4; j++)
        acc[i][j] = __builtin_amdgcn_mfma_f32_16x16x32_bf16(af[i], bfv[j], acc[i][j], 0, 0, 0);
    __syncthreads();
  }
  const bool addb = (MODE == 5) && bias && (blockIdx.z == 0);
#pragma unroll
  for (int i = 0; i < 4; i++)
#pragma unroll
    for (int j = 0; j < 4; j++)
#pragma unroll
      for (int r = 0; r < 4; r++) {
        const int m = bm + wm + i * 16 + quad * 4 + r;
        const int n = bn + wn + j * 16 + l16;
        const size_t idx = (size_t)m * N + n;
        const float v = acc[i][j][r];
        if (MODE == 2) {
          // tanh-GELU via native exp2: g = z*t/(t+1), t = exp2(2.88539*u)
          const float z = v + bias[n];
          const float u = z * (0.7978845608f + 0.03567740814f * z * z);
          const float e = fminf(u * 2.885390082f, 80.f);
          const float tt = exp2fast(e);
          outb[idx] = f2b(z * tt * rcpfast(tt + 1.0f));
        } else if (MODE == 4) {
          outb[idx] = f2b(v);
        } else {  // MODE 5: split-K atomic accumulate
          atomicAdd(outf + idx, addb ? v + bias[n] : v);
        }
      }
}

// ---------------- RoPE: qkv(bf16,[S,3,NH,HD]) -> qh,kh ([seg,NH,L,HD]) -----
__device__ __forceinline__ u32 rope2(u32 in, float c, float sn, float sc) {
  const float a = b2f((unsigned short)(in & 0xffff));
  const float b = b2f((unsigned short)(in >> 16));
  return (u32)f2b((a * c - b * sn) * sc) | ((u32)f2b((a * sn + b * c) * sc) << 16);
}
__global__ __launch_bounds__(256) void rope_kernel(const unsigned short* __restrict__ qkv,
                                                   const float* __restrict__ cb,
                                                   const float* __restrict__ sb,
                                                   unsigned short* __restrict__ qh,
                                                   unsigned short* __restrict__ kh) {
  const int tid = blockIdx.x * 256 + threadIdx.x;  // S*NH*8 threads
  const int ii = tid & 7, head = (tid >> 3) & 15, s = tid >> 7;
  const float4 cv = *(const float4*)(cb + s * 32 + ii * 4);
  const float4 sv = *(const float4*)(sb + s * 32 + ii * 4);
  const unsigned short* base = qkv + (size_t)s * 3072 + head * 64 + ii * 8;
  const uint4 qa = *(const uint4*)base;
  const uint4 ka = *(const uint4*)(base + 1024);
  const int seg = s >> 10, l = s & 1023;
  const size_t o = ((size_t)((seg * 16 + head) * 1024 + l)) * 64 + ii * 8;
  const float QSC = 0.125f * 1.44269504f;
  uint4 qo, ko;
  qo.x = rope2(qa.x, cv.x, sv.x, QSC); ko.x = rope2(ka.x, cv.x, sv.x, 1.f);
  qo.y = rope2(qa.y, cv.y, sv.y, QSC); ko.y = rope2(ka.y, cv.y, sv.y, 1.f);
  qo.z = rope2(qa.z, cv.z, sv.z, QSC); ko.z = rope2(ka.z, cv.z, sv.z, 1.f);
  qo.w = rope2(qa.w, cv.w, sv.w, QSC); ko.w = rope2(ka.w, cv.w, sv.w, 1.f);
  *(uint4*)(qh + o) = qo;
  *(uint4*)(kh + o) = ko;
}

// ---------------- V transpose: qkv v-part -> vt [seg,NH,HD,L] --------------
__global__ __launch_bounds__(256) void vtrans_kernel(const unsigned short* __restrict__ qkv,
                                                     unsigned short* __restrict__ vt) {
  __shared__ unsigned short tile[64][72];
  const int b = blockIdx.x;  // 8*16*16
  const int lt = b & 15, head = (b >> 4) & 15, seg = b >> 8;
  const int t = threadIdx.x;
  const int r = t >> 2, c0 = (t & 3) * 16;
  const unsigned short* src =
      qkv + ((size_t)(seg * 1024 + lt * 64 + r)) * 3072 + 2048 + head * 64 + c0;
#pragma unroll
  for (int k = 0; k < 16; k++) tile[r][c0 + k] = src[k];
  __syncthreads();
  unsigned short* dst =
      vt + ((size_t)((seg * 16 + head) * 64 + r)) * 1024 + lt * 64 + c0;
#pragma unroll
  for (int k = 0; k < 16; k++) dst[k] = tile[c0 + k][r];
}

// ---------------- flash attention, 32x32x16 MFMA, in-register P ------------
__global__ __launch_bounds__(256) void attn_kernel(const unsigned short* __restrict__ qh,
                                                   const unsigned short* __restrict__ kh,
                                                   const unsigned short* __restrict__ vt,
                                                   unsigned short* __restrict__ out) {
  __shared__ __align__(16) unsigned short Qs[128 * 64];
  __shared__ __align__(16) unsigned short Ks[64 * 64];
  __shared__ __align__(16) unsigned short Vs[64 * 64];  // [hd][key]
  __shared__ float wl[128];
  const int b = blockIdx.x;
  const int head = b & 15, seg = (b >> 4) & 7, qt = b >> 7;
  const int t = threadIdx.x, wave = t >> 6, lane = t & 63;
  const int h = lane >> 5, q31 = lane & 31;
  const size_t sh = (size_t)(seg * 16 + head);
  const unsigned short* qbase = qh + (sh * 1024 + (size_t)qt * 128) * 64;
  const unsigned short* kbase = kh + sh * 1024 * 64;
  const unsigned short* vbase = vt + sh * 64 * 1024;
  const int r8 = lane >> 3;
  const int c8 = ((lane & 7) ^ (r8 & 7)) * 8;  // swizzled source col (shorts)
#pragma unroll
  for (int cc = 0; cc < 4; cc++) {  // stage Q once (16KB, 16 chunks)
    const int chunk = wave * 4 + cc;
    async_ld16(qbase + (size_t)(chunk * 8 + r8) * 64 + c8, Qs + chunk * 512);
  }
  const int qrow_l = wave * 32 + q31;          // this lane's query row in tile
  const int qsw = qrow_l & 7;                  // Qs swizzle key
  bf16x8 qf[4];                                // Q B-frags, loaded once
  float lsum = 0.f;
  f32x16 oacc[2] = {};

  for (int kt = 0; kt < 16; kt++) {
    const int ch0 = wave * 2;
    async_ld16(kbase + (size_t)(kt * 64 + ch0 * 8 + r8) * 64 + c8, Ks + ch0 * 512);
    async_ld16(kbase + (size_t)(kt * 64 + ch0 * 8 + 8 + r8) * 64 + c8, Ks + ch0 * 512 + 512);
    async_ld16(vbase + (size_t)(ch0 * 8 + r8) * 1024 + kt * 64 + c8, Vs + ch0 * 512);
    async_ld16(vbase + (size_t)(ch0 * 8 + 8 + r8) * 1024 + kt * 64 + c8, Vs + ch0 * 512 + 512);
    __syncthreads();
    if (kt == 0) {
#pragma unroll
      for (int ks = 0; ks < 4; ks++)
        qf[ks] = *(const bf16x8*)(Qs + qrow_l * 64 + (((2 * ks + h) ^ qsw)) * 8);
    }
    // S^T = K.Q^T : 2 key tiles x 4 ksteps
    f32x16 st[2] = {{}, {}};
#pragma unroll
    for (int T = 0; T < 2; T++) {
      const int krow = 32 * T + q31;
      const int ksw = krow & 7;
#pragma unroll
      for (int ks = 0; ks < 4; ks++) {
        const bf16x8 kf = *(const bf16x8*)(Ks + krow * 64 + (((2 * ks + h) ^ ksw)) * 8);
        st[T] = __builtin_amdgcn_mfma_f32_32x32x16_bf16(kf, qf[ks], st[T], 0, 0, 0);
      }
    }
    // p = exp2(s) (q pre-scaled by log2e/8); pack bf16 pairs per group
    u32 pk[2][4][2];
#pragma unroll
    for (int T = 0; T < 2; T++)
#pragma unroll
      for (int g = 0; g < 4; g++)
#pragma unroll
        for (int e = 0; e < 2; e++) {
          const float plo = exp2fast(st[T][4 * g + 2 * e]);
          const float phi = exp2fast(st[T][4 * g + 2 * e + 1]);
          lsum += plo + phi;
          pk[T][g][e] = (u32)f2b(plo) | ((u32)f2b(phi) << 16);
        }
    // half-wave exchange of the cross quads
    u32 rcv[2][4];
#pragma unroll
    for (int T = 0; T < 2; T++) {
      const u32 p0 = h ? pk[T][0][0] : pk[T][1][0];
      const u32 p1 = h ? pk[T][0][1] : pk[T][1][1];
      const u32 p2 = h ? pk[T][2][0] : pk[T][3][0];
      const u32 p3 = h ? pk[T][2][1] : pk[T][3][1];
      rcv[T][0] = (u32)__shfl_xor((int)p0, 32, 64);
      rcv[T][1] = (u32)__shfl_xor((int)p1, 32, 64);
      rcv[T][2] = (u32)__shfl_xor((int)p2, 32, 64);
      rcv[T][3] = (u32)__shfl_xor((int)p3, 32, 64);
    }
    // O += P.V
#pragma unroll
    for (int tt = 0; tt < 4; tt++) {
      const int T = tt >> 1, uu = tt & 1;
      union { u32 u[4]; bf16x8 v; } af;
      if (h == 0) {
        af.u[0] = pk[T][2 * uu][0];
        af.u[1] = pk[T][2 * uu][1];
        af.u[2] = rcv[T][2 * uu];
        af.u[3] = rcv[T][2 * uu + 1];
      } else {
        af.u[0] = rcv[T][2 * uu];
        af.u[1] = rcv[T][2 * uu + 1];
        af.u[2] = pk[T][2 * uu + 1][0];
        af.u[3] = pk[T][2 * uu + 1][1];
      }
#pragma unroll
      for (int ot = 0; ot < 2; ot++) {
        const int vrow = 32 * ot + q31;
        const int vsw = vrow & 7;
        const bf16x8 bv = *(const bf16x8*)(Vs + vrow * 64 + (((2 * tt + h) ^ vsw)) * 8);
        oacc[ot] = __builtin_amdgcn_mfma_f32_32x32x16_bf16(af.v, bv, oacc[ot], 0, 0, 0);
      }
    }
    __syncthreads();
  }
  // epilogue: full row-sum, normalize, store
  lsum += __shfl_xor(lsum, 32, 64);
  if (h == 0) wl[wave * 32 + q31] = lsum;
  const int qglob = seg * 1024 + qt * 128 + wave * 32;
#pragma unroll
  for (int g = 0; g < 4; g++) {
    const float4 lv = *(const float4*)&wl[wave * 32 + 8 * g + 4 * h];
#pragma unroll
    for (int m = 0; m < 4; m++) {
      const int r16 = 4 * g + m;
      const int qrow = qglob + m + 8 * g + 4 * h;
      const float invl = rcpfast((&lv.x)[m]);
#pragma unroll
      for (int ot = 0; ot < 2; ot++)
        out[(size_t)qrow * 1024 + head * 64 + 32 * ot + q31] = f2b(oacc[ot][r16] * invl);
    }
  }
}

// ---------------------------------------------------------------------------
extern "C" void kernel_launch(void* const* d_in, const int* in_sizes, int n_in,
                              void* d_out, int out_size, void* d_ws, size_t ws_size,
                              hipStream_t stream) {
  (void)in_sizes; (void)n_in; (void)out_size; (void)ws_size;
  const float* x    = (const float*)d_in[0];
  const float* wqkv = (const float*)d_in[1];
  const float* wo   = (const float*)d_in[2];
  const float* ln0g = (const float*)d_in[3];
  const float* ln0b = (const float*)d_in[4];
  const float* ln1g = (const float*)d_in[5];
  const float* ln1b = (const float*)d_in[6];
  const float* fc0w = (const float*)d_in[7];
  const float* fc0b = (const float*)d_in[8];
  const float* fc1w = (const float*)d_in[9];
  const float* fc1b = (const float*)d_in[10];
  const float* rc   = (const float*)d_in[11];
  const float* rsn  = (const float*)d_in[12];
  float* out = (float*)d_out;
  char* w = (char*)d_ws;
  const size_t MB = 1u << 20;
  unsigned short* hb    = (unsigned short*)(w + 0);
  unsigned short* bqkv  = (unsigned short*)(w + 16 * MB);
  unsigned short* bwo   = (unsigned short*)(w + 22 * MB);
  unsigned short* bfc0  = (unsigned short*)(w + 24 * MB);
  unsigned short* bfc1  = (unsigned short*)(w + 32 * MB);
  unsigned short* qhb   = (unsigned short*)(w + 40 * MB);
  unsigned short* khb   = (unsigned short*)(w + 56 * MB);
  unsigned short* vtb   = (unsigned short*)(w + 72 * MB);
  unsigned short* attnb = (unsigned short*)(w + 88 * MB);
  unsigned short* qkvb  = (unsigned short*)(w + 104 * MB);
  unsigned short* midb  = (unsigned short*)(w + 104 * MB);  // alias, qkvb dead by then

  // seed residual base: out = x (WO and FC1 atomically accumulate into it)
  hipMemcpyAsync(out, x, (size_t)8192 * 1024 * 4, hipMemcpyDeviceToDevice, stream);
  castall_kernel<<<12288, 256, 0, stream>>>(wqkv, wo, fc0w, fc1w, bqkv);
  ln_kernel<<<8192, 256, 0, stream>>>(x, ln0g, ln0b, hb);
  gemm_bt<4><<<dim3(24, 64), 256, 0, stream>>>(hb, bqkv, 8192, 3072, 1024,
                                               nullptr, qkvb, nullptr);
  rope_kernel<<<4096, 256, 0, stream>>>(qkvb, rc, rsn, qhb, khb);
  vtrans_kernel<<<2048, 256, 0, stream>>>(qkvb, vtb);
  attn_kernel<<<1024, 256, 0, stream>>>(qhb, khb, vtb, attnb);
  // WO: out += attn @ wo^T   (split-K x2, atomic epilogue)
  gemm_bt<5><<<dim3(8, 64, 2), 256, 0, stream>>>(attnb, bwo, 8192, 1024, 1024,
                                                 out, nullptr, nullptr);
  ln_kernel<<<8192, 256, 0, stream>>>(out, ln1g, ln1b, hb);
  gemm_bt<2><<<dim3(32, 64), 256, 0, stream>>>(hb, bfc0, 8192, 4096, 1024,
                                               nullptr, midb, fc0b);
  // FC1: out += mid @ fc1^T + bias   (split-K x2, atomic epilogue)
  gemm_bt<5><<<dim3(8, 64, 2), 256, 0, stream>>>(midb, bfc1, 8192, 1024, 4096,
                                                 out, nullptr, fc1b);
}

// Round 6
// 586.930 us; speedup vs baseline: 1.0486x; 1.0486x over previous
//
#include <hip/hip_runtime.h>
#include <math.h>

// ---------------------------------------------------------------------------
// VideoChat3 vision encoder block, bf16-MFMA pipeline. Round 6 (r5 + fix):
//  - fix: castln_kernel param/local name collision (s2) -> params w0..w3
//  - FC1 split-K=2: z0 -> direct out=acc+bias+res, z1 -> fp32 partial in dead
//    qh/kh workspace; float4 reduce "out += p1" afterwards (no atomics)
//  - fused cast+LN0 kernel, fused RoPE+Vtranspose kernel
// S=8192, H=1024, NH=16, HD=64, NSEG=8, L=1024, MLP=4096.
// ---------------------------------------------------------------------------

typedef __bf16 bf16x8 __attribute__((ext_vector_type(8)));
typedef float f32x4 __attribute__((ext_vector_type(4)));
typedef float f32x16 __attribute__((ext_vector_type(16)));
typedef unsigned int u32;

__device__ __forceinline__ unsigned short f2b(float f) {  // RNE f32->bf16
  unsigned u = __float_as_uint(f);
  return (unsigned short)((u + 0x7FFFu + ((u >> 16) & 1u)) >> 16);
}
__device__ __forceinline__ float b2f(unsigned short h) {
  return __uint_as_float(((unsigned)h) << 16);
}
__device__ __forceinline__ void async_ld16(const void* g, void* l) {
  __builtin_amdgcn_global_load_lds((__attribute__((address_space(1))) void*)g,
                                   (__attribute__((address_space(3))) void*)l,
                                   16, 0, 0);
}
__device__ __forceinline__ float exp2fast(float x) {
#if __has_builtin(__builtin_amdgcn_exp2f)
  return __builtin_amdgcn_exp2f(x);
#else
  return exp2f(x);
#endif
}
__device__ __forceinline__ float rcpfast(float x) {
#if __has_builtin(__builtin_amdgcn_rcpf)
  return __builtin_amdgcn_rcpf(x);
#else
  return 1.0f / x;
#endif
}

// ---------------- fused: weight cast fp32->bf16  +  LN0 --------------------
// blocks [0,12288): cast 4 weight mats into contiguous bf16 region
// blocks [12288,20480): layernorm row (blk-12288) of x -> hb
__global__ __launch_bounds__(256) void castln_kernel(
    const float* __restrict__ w0, const float* __restrict__ w1,
    const float* __restrict__ w2, const float* __restrict__ w3,
    unsigned short* __restrict__ wdst,
    const float* __restrict__ x, const float* __restrict__ g,
    const float* __restrict__ bt, unsigned short* __restrict__ hout) {
  __shared__ float red[8];
  const int blk = blockIdx.x;
  if (blk < 12288) {
    const int t = blk * 256 + threadIdx.x;  // float4 groups
    const float* src;
    int off;
    if (t < 786432) { src = w0; off = t; }
    else if (t < 1048576) { src = w1; off = t - 786432; }
    else if (t < 2097152) { src = w2; off = t - 1048576; }
    else { src = w3; off = t - 2097152; }
    const float4 v = ((const float4*)src)[off];
    ushort4 o;
    o.x = f2b(v.x); o.y = f2b(v.y); o.z = f2b(v.z); o.w = f2b(v.w);
    ((ushort4*)wdst)[t] = o;
    return;
  }
  const int row = blk - 12288, t = threadIdx.x;
  const float4 v = ((const float4*)(x + (size_t)row * 1024))[t];
  float s = v.x + v.y + v.z + v.w;
  float s2 = v.x * v.x + v.y * v.y + v.z * v.z + v.w * v.w;
#pragma unroll
  for (int m = 1; m < 64; m <<= 1) {
    s += __shfl_xor(s, m, 64);
    s2 += __shfl_xor(s2, m, 64);
  }
  if ((t & 63) == 0) { red[t >> 6] = s; red[4 + (t >> 6)] = s2; }
  __syncthreads();
  const float ts = red[0] + red[1] + red[2] + red[3];
  const float ts2 = red[4] + red[5] + red[6] + red[7];
  const float mean = ts * (1.f / 1024.f);
  const float var = ts2 * (1.f / 1024.f) - mean * mean;
  const float inv = rsqrtf(var + 1e-5f);
  const float4 gv = ((const float4*)g)[t];
  const float4 bv = ((const float4*)bt)[t];
  ushort4 o;
  o.x = f2b((v.x - mean) * inv * gv.x + bv.x);
  o.y = f2b((v.y - mean) * inv * gv.y + bv.y);
  o.z = f2b((v.z - mean) * inv * gv.z + bv.z);
  o.w = f2b((v.w - mean) * inv * gv.w + bv.w);
  ((ushort4*)hout)[(size_t)row * 256 + t] = o;
}

// ---------------- layernorm (row of 1024) -> bf16 (standalone, LN1) --------
__global__ __launch_bounds__(256) void ln_kernel(const float* __restrict__ x,
                                                 const float* __restrict__ g,
                                                 const float* __restrict__ bt,
                                                 unsigned short* __restrict__ out) {
  __shared__ float red[8];
  const int row = blockIdx.x, t = threadIdx.x;
  const float4 v = ((const float4*)(x + (size_t)row * 1024))[t];
  float s = v.x + v.y + v.z + v.w;
  float s2 = v.x * v.x + v.y * v.y + v.z * v.z + v.w * v.w;
#pragma unroll
  for (int m = 1; m < 64; m <<= 1) {
    s += __shfl_xor(s, m, 64);
    s2 += __shfl_xor(s2, m, 64);
  }
  if ((t & 63) == 0) { red[t >> 6] = s; red[4 + (t >> 6)] = s2; }
  __syncthreads();
  const float ts = red[0] + red[1] + red[2] + red[3];
  const float ts2 = red[4] + red[5] + red[6] + red[7];
  const float mean = ts * (1.f / 1024.f);
  const float var = ts2 * (1.f / 1024.f) - mean * mean;
  const float inv = rsqrtf(var + 1e-5f);
  const float4 gv = ((const float4*)g)[t];
  const float4 bv = ((const float4*)bt)[t];
  ushort4 o;
  o.x = f2b((v.x - mean) * inv * gv.x + bv.x);
  o.y = f2b((v.y - mean) * inv * gv.y + bv.y);
  o.z = f2b((v.z - mean) * inv * gv.z + bv.z);
  o.w = f2b((v.w - mean) * inv * gv.w + bv.w);
  ((ushort4*)out)[(size_t)row * 256 + t] = o;
}

// ---------------- GEMM: C[M,N] = A[M,K] @ B[N,K]^T, bf16 in, fp32 acc ------
// 128x128 tile, 4 waves, 16x16x32 MFMA, XOR-swizzled LDS (conflict-free).
// MODE 1: outf = acc + res                      (fp32; WO + residual)
// MODE 2: outb = bf16(gelu(acc + bias))         (FC0)
// MODE 4: outb = bf16(acc)                      (QKV)
// MODE 6: split-K=2 (gridDim.z==2): z0 -> outf = acc + bias + res (direct),
//         z1 -> part = acc (fp32 partial; reduced by addp_kernel)
template <int MODE>
__global__ __launch_bounds__(256) void gemm_bt(
    const unsigned short* __restrict__ A, const unsigned short* __restrict__ B,
    int M, int N, int K, float* __restrict__ outf, unsigned short* __restrict__ outb,
    const float* __restrict__ res, const float* __restrict__ bias,
    float* __restrict__ part) {
  __shared__ __align__(16) unsigned short As[128 * 32];
  __shared__ __align__(16) unsigned short Bs[128 * 32];
  const int bm = blockIdx.y * 128, bn = blockIdx.x * 128;
  const int Kper = K / gridDim.z;
  const int kbeg = blockIdx.z * Kper, kend = kbeg + Kper;
  const int t = threadIdx.x, wave = t >> 6, lane = t & 63;
  const int quad = lane >> 4, l16 = lane & 15;
  const int wm = (wave >> 1) * 64, wn = (wave & 1) * 64;
  const int srow = lane >> 2;
  const int scol = (((lane & 3) ^ ((lane >> 3) & 3)) * 8);  // swizzled source col
  const unsigned short* Ag0 = A + (size_t)(bm + wave * 32 + srow) * K + scol;
  const unsigned short* Ag1 = Ag0 + (size_t)16 * K;
  const unsigned short* Bg0 = B + (size_t)(bn + wave * 32 + srow) * K + scol;
  const unsigned short* Bg1 = Bg0 + (size_t)16 * K;
  unsigned short* Al = As + wave * 1024;
  unsigned short* Bl = Bs + wave * 1024;
  const int swg = (l16 >> 1) & 3;  // read-side swizzle key
  f32x4 acc[4][4] = {};
  for (int k0 = kbeg; k0 < kend; k0 += 32) {
    async_ld16(Ag0 + k0, Al);
    async_ld16(Ag1 + k0, Al + 512);
    async_ld16(Bg0 + k0, Bl);
    async_ld16(Bg1 + k0, Bl + 512);
    __syncthreads();
    bf16x8 af[4], bfv[4];
#pragma unroll
    for (int i = 0; i < 4; i++)
      af[i] = *(const bf16x8*)(As + (wm + i * 16 + l16) * 32 + (quad ^ swg) * 8);
#pragma unroll
    for (int j = 0; j < 4; j++)
      bfv[j] = *(const bf16x8*)(Bs + (wn + j * 16 + l16) * 32 + (quad ^ swg) * 8);
#pragma unroll
    for (int i = 0; i < 4; i++)
#pragma unroll
      for (int j = 0; j < 4; j++)
        acc[i][j] = __builtin_amdgcn_mfma_f32_16x16x32_bf16(af[i], bfv[j], acc[i][j], 0, 0, 0);
    __syncthreads();
  }
#pragma unroll
  for (int i = 0; i < 4; i++)
#pragma unroll
    for (int j = 0; j < 4; j++)
#pragma unroll
      for (int r = 0; r < 4; r++) {
        const int m = bm + wm + i * 16 + quad * 4 + r;
        const int n = bn + wn + j * 16 + l16;
        const size_t idx = (size_t)m * N + n;
        const float v = acc[i][j][r];
        if (MODE == 1) {
          outf[idx] = v + res[idx];
        } else if (MODE == 2) {
          // tanh-GELU via native exp2: g = z*t/(t+1), t = exp2(2.88539*u)
          const float z = v + bias[n];
          const float u = z * (0.7978845608f + 0.03567740814f * z * z);
          const float e = fminf(u * 2.885390082f, 80.f);
          const float tt = exp2fast(e);
          outb[idx] = f2b(z * tt * rcpfast(tt + 1.0f));
        } else if (MODE == 4) {
          outb[idx] = f2b(v);
        } else {  // MODE 6: split-K, no atomics
          if (blockIdx.z == 0) outf[idx] = v + bias[n] + res[idx];
          else part[idx] = v;
        }
      }
}

// ---------------- reduce: out += p (float4) --------------------------------
__global__ __launch_bounds__(256) void addp_kernel(float* __restrict__ out,
                                                   const float* __restrict__ p) {
  const int t = blockIdx.x * 256 + threadIdx.x;
  float4 a = ((const float4*)out)[t];
  const float4 b = ((const float4*)p)[t];
  a.x += b.x; a.y += b.y; a.z += b.z; a.w += b.w;
  ((float4*)out)[t] = a;
}

// ---------------- fused RoPE + V-transpose ---------------------------------
// blocks [0,4096): rope  qkv -> qh,kh ([seg,NH,L,HD]); q prescale 1/8*log2e
// blocks [4096,6144): vtrans  qkv v-part -> vt [seg,NH,HD,L]
__device__ __forceinline__ u32 rope2(u32 in, float c, float sn, float sc) {
  const float a = b2f((unsigned short)(in & 0xffff));
  const float b = b2f((unsigned short)(in >> 16));
  return (u32)f2b((a * c - b * sn) * sc) | ((u32)f2b((a * sn + b * c) * sc) << 16);
}
__global__ __launch_bounds__(256) void ropevt_kernel(const unsigned short* __restrict__ qkv,
                                                     const float* __restrict__ cb,
                                                     const float* __restrict__ sb,
                                                     unsigned short* __restrict__ qh,
                                                     unsigned short* __restrict__ kh,
                                                     unsigned short* __restrict__ vt) {
  __shared__ unsigned short tile[64][72];
  const int blk = blockIdx.x;
  if (blk < 4096) {
    const int tid = blk * 256 + threadIdx.x;  // S*NH*8 threads
    const int ii = tid & 7, head = (tid >> 3) & 15, s = tid >> 7;
    const float4 cv = *(const float4*)(cb + s * 32 + ii * 4);
    const float4 sv = *(const float4*)(sb + s * 32 + ii * 4);
    const unsigned short* base = qkv + (size_t)s * 3072 + head * 64 + ii * 8;
    const uint4 qa = *(const uint4*)base;
    const uint4 ka = *(const uint4*)(base + 1024);
    const int seg = s >> 10, l = s & 1023;
    const size_t o = ((size_t)((seg * 16 + head) * 1024 + l)) * 64 + ii * 8;
    const float QSC = 0.125f * 1.44269504f;
    uint4 qo, ko;
    qo.x = rope2(qa.x, cv.x, sv.x, QSC); ko.x = rope2(ka.x, cv.x, sv.x, 1.f);
    qo.y = rope2(qa.y, cv.y, sv.y, QSC); ko.y = rope2(ka.y, cv.y, sv.y, 1.f);
    qo.z = rope2(qa.z, cv.z, sv.z, QSC); ko.z = rope2(ka.z, cv.z, sv.z, 1.f);
    qo.w = rope2(qa.w, cv.w, sv.w, QSC); ko.w = rope2(ka.w, cv.w, sv.w, 1.f);
    *(uint4*)(qh + o) = qo;
    *(uint4*)(kh + o) = ko;
    return;
  }
  const int b = blk - 4096;  // 8*16*16
  const int lt = b & 15, head = (b >> 4) & 15, seg = b >> 8;
  const int t = threadIdx.x;
  const int r = t >> 2, c0 = (t & 3) * 16;
  const unsigned short* src =
      qkv + ((size_t)(seg * 1024 + lt * 64 + r)) * 3072 + 2048 + head * 64 + c0;
#pragma unroll
  for (int k = 0; k < 16; k++) tile[r][c0 + k] = src[k];
  __syncthreads();
  unsigned short* dst =
      vt + ((size_t)((seg * 16 + head) * 64 + r)) * 1024 + lt * 64 + c0;
#pragma unroll
  for (int k = 0; k < 16; k++) dst[k] = tile[c0 + k][r];
}

// ---------------- flash attention, 32x32x16 MFMA, in-register P ------------
__global__ __launch_bounds__(256) void attn_kernel(const unsigned short* __restrict__ qh,
                                                   const unsigned short* __restrict__ kh,
                                                   const unsigned short* __restrict__ vt,
                                                   unsigned short* __restrict__ out) {
  __shared__ __align__(16) unsigned short Qs[128 * 64];
  __shared__ __align__(16) unsigned short Ks[64 * 64];
  __shared__ __align__(16) unsigned short Vs[64 * 64];  // [hd][key]
  __shared__ float wl[128];
  const int b = blockIdx.x;
  const int head = b & 15, seg = (b >> 4) & 7, qt = b >> 7;
  const int t = threadIdx.x, wave = t >> 6, lane = t & 63;
  const int h = lane >> 5, q31 = lane & 31;
  const size_t sh = (size_t)(seg * 16 + head);
  const unsigned short* qbase = qh + (sh * 1024 + (size_t)qt * 128) * 64;
  const unsigned short* kbase = kh + sh * 1024 * 64;
  const unsigned short* vbase = vt + sh * 64 * 1024;
  const int r8 = lane >> 3;
  const int c8 = ((lane & 7) ^ (r8 & 7)) * 8;  // swizzled source col (shorts)
#pragma unroll
  for (int cc = 0; cc < 4; cc++) {  // stage Q once (16KB, 16 chunks)
    const int chunk = wave * 4 + cc;
    async_ld16(qbase + (size_t)(chunk * 8 + r8) * 64 + c8, Qs + chunk * 512);
  }
  const int qrow_l = wave * 32 + q31;          // this lane's query row in tile
  const int qsw = qrow_l & 7;                  // Qs swizzle key
  bf16x8 qf[4];                                // Q B-frags, loaded once
  float lsum = 0.f;
  f32x16 oacc[2] = {};

  for (int kt = 0; kt < 16; kt++) {
    const int ch0 = wave * 2;
    async_ld16(kbase + (size_t)(kt * 64 + ch0 * 8 + r8) * 64 + c8, Ks + ch0 * 512);
    async_ld16(kbase + (size_t)(kt * 64 + ch0 * 8 + 8 + r8) * 64 + c8, Ks + ch0 * 512 + 512);
    async_ld16(vbase + (size_t)(ch0 * 8 + r8) * 1024 + kt * 64 + c8, Vs + ch0 * 512);
    async_ld16(vbase + (size_t)(ch0 * 8 + 8 + r8) * 1024 + kt * 64 + c8, Vs + ch0 * 512 + 512);
    __syncthreads();
    if (kt == 0) {
#pragma unroll
      for (int ks = 0; ks < 4; ks++)
        qf[ks] = *(const bf16x8*)(Qs + qrow_l * 64 + (((2 * ks + h) ^ qsw)) * 8);
    }
    // S^T = K.Q^T : 2 key tiles x 4 ksteps
    f32x16 st[2] = {{}, {}};
#pragma unroll
    for (int T = 0; T < 2; T++) {
      const int krow = 32 * T + q31;
      const int ksw = krow & 7;
#pragma unroll
      for (int ks = 0; ks < 4; ks++) {
        const bf16x8 kf = *(const bf16x8*)(Ks + krow * 64 + (((2 * ks + h) ^ ksw)) * 8);
        st[T] = __builtin_amdgcn_mfma_f32_32x32x16_bf16(kf, qf[ks], st[T], 0, 0, 0);
      }
    }
    // p = exp2(s) (q pre-scaled by log2e/8); pack bf16 pairs per group
    u32 pk[2][4][2];
#pragma unroll
    for (int T = 0; T < 2; T++)
#pragma unroll
      for (int g = 0; g < 4; g++)
#pragma unroll
        for (int e = 0; e < 2; e++) {
          const float plo = exp2fast(st[T][4 * g + 2 * e]);
          const float phi = exp2fast(st[T][4 * g + 2 * e + 1]);
          lsum += plo + phi;
          pk[T][g][e] = (u32)f2b(plo) | ((u32)f2b(phi) << 16);
        }
    // half-wave exchange of the cross quads
    u32 rcv[2][4];
#pragma unroll
    for (int T = 0; T < 2; T++) {
      const u32 p0 = h ? pk[T][0][0] : pk[T][1][0];
      const u32 p1 = h ? pk[T][0][1] : pk[T][1][1];
      const u32 p2 = h ? pk[T][2][0] : pk[T][3][0];
      const u32 p3 = h ? pk[T][2][1] : pk[T][3][1];
      rcv[T][0] = (u32)__shfl_xor((int)p0, 32, 64);
      rcv[T][1] = (u32)__shfl_xor((int)p1, 32, 64);
      rcv[T][2] = (u32)__shfl_xor((int)p2, 32, 64);
      rcv[T][3] = (u32)__shfl_xor((int)p3, 32, 64);
    }
    // O += P.V
#pragma unroll
    for (int tt = 0; tt < 4; tt++) {
      const int T = tt >> 1, uu = tt & 1;
      union { u32 u[4]; bf16x8 v; } af;
      if (h == 0) {
        af.u[0] = pk[T][2 * uu][0];
        af.u[1] = pk[T][2 * uu][1];
        af.u[2] = rcv[T][2 * uu];
        af.u[3] = rcv[T][2 * uu + 1];
      } else {
        af.u[0] = rcv[T][2 * uu];
        af.u[1] = rcv[T][2 * uu + 1];
        af.u[2] = pk[T][2 * uu + 1][0];
        af.u[3] = pk[T][2 * uu + 1][1];
      }
#pragma unroll
      for (int ot = 0; ot < 2; ot++) {
        const int vrow = 32 * ot + q31;
        const int vsw = vrow & 7;
        const bf16x8 bv = *(const bf16x8*)(Vs + vrow * 64 + (((2 * tt + h) ^ vsw)) * 8);
        oacc[ot] = __builtin_amdgcn_mfma_f32_32x32x16_bf16(af.v, bv, oacc[ot], 0, 0, 0);
      }
    }
    __syncthreads();
  }
  // epilogue: full row-sum, normalize, store
  lsum += __shfl_xor(lsum, 32, 64);
  if (h == 0) wl[wave * 32 + q31] = lsum;
  const int qglob = seg * 1024 + qt * 128 + wave * 32;
#pragma unroll
  for (int g = 0; g < 4; g++) {
    const float4 lv = *(const float4*)&wl[wave * 32 + 8 * g + 4 * h];
#pragma unroll
    for (int m = 0; m < 4; m++) {
      const int r16 = 4 * g + m;
      const int qrow = qglob + m + 8 * g + 4 * h;
      const float invl = rcpfast((&lv.x)[m]);
#pragma unroll
      for (int ot = 0; ot < 2; ot++)
        out[(size_t)qrow * 1024 + head * 64 + 32 * ot + q31] = f2b(oacc[ot][r16] * invl);
    }
  }
}

// ---------------------------------------------------------------------------
extern "C" void kernel_launch(void* const* d_in, const int* in_sizes, int n_in,
                              void* d_out, int out_size, void* d_ws, size_t ws_size,
                              hipStream_t stream) {
  (void)in_sizes; (void)n_in; (void)out_size; (void)ws_size;
  const float* x    = (const float*)d_in[0];
  const float* wqkv = (const float*)d_in[1];
  const float* wo   = (const float*)d_in[2];
  const float* ln0g = (const float*)d_in[3];
  const float* ln0b = (const float*)d_in[4];
  const float* ln1g = (const float*)d_in[5];
  const float* ln1b = (const float*)d_in[6];
  const float* fc0w = (const float*)d_in[7];
  const float* fc0b = (const float*)d_in[8];
  const float* fc1w = (const float*)d_in[9];
  const float* fc1b = (const float*)d_in[10];
  const float* rc   = (const float*)d_in[11];
  const float* rsn  = (const float*)d_in[12];
  float* out = (float*)d_out;
  char* w = (char*)d_ws;
  const size_t MB = 1u << 20;
  unsigned short* hb    = (unsigned short*)(w + 0);
  unsigned short* bqkv  = (unsigned short*)(w + 16 * MB);
  unsigned short* bwo   = (unsigned short*)(w + 22 * MB);
  unsigned short* bfc0  = (unsigned short*)(w + 24 * MB);
  unsigned short* bfc1  = (unsigned short*)(w + 32 * MB);
  unsigned short* qhb   = (unsigned short*)(w + 40 * MB);
  unsigned short* khb   = (unsigned short*)(w + 56 * MB);
  unsigned short* vtb   = (unsigned short*)(w + 72 * MB);
  unsigned short* attnb = (unsigned short*)(w + 88 * MB);
  unsigned short* qkvb  = (unsigned short*)(w + 104 * MB);
  unsigned short* midb  = (unsigned short*)(w + 104 * MB);  // alias, qkvb dead
  float* p1 = (float*)(w + 40 * MB);  // FC1 split-K partial (qh/kh dead by then)

  // 1: weight casts + LN0 (independent, one dispatch)
  castln_kernel<<<20480, 256, 0, stream>>>(wqkv, wo, fc0w, fc1w, bqkv,
                                           x, ln0g, ln0b, hb);
  // 2: QKV = hb @ wqkv^T
  gemm_bt<4><<<dim3(24, 64), 256, 0, stream>>>(hb, bqkv, 8192, 3072, 1024,
                                               nullptr, qkvb, nullptr, nullptr, nullptr);
  // 3: RoPE + V-transpose (one dispatch)
  ropevt_kernel<<<6144, 256, 0, stream>>>(qkvb, rc, rsn, qhb, khb, vtb);
  // 4: attention
  attn_kernel<<<1024, 256, 0, stream>>>(qhb, khb, vtb, attnb);
  // 5: WO: out = attn @ wo^T + x
  gemm_bt<1><<<dim3(8, 64), 256, 0, stream>>>(attnb, bwo, 8192, 1024, 1024,
                                              out, nullptr, x, nullptr, nullptr);
  // 6: LN1
  ln_kernel<<<8192, 256, 0, stream>>>(out, ln1g, ln1b, hb);
  // 7: FC0 (+bias, GELU) -> midb
  gemm_bt<2><<<dim3(32, 64), 256, 0, stream>>>(hb, bfc0, 8192, 4096, 1024,
                                               nullptr, midb, nullptr, fc0b, nullptr);
  // 8: FC1 split-K=2: z0 -> out = acc + bias + out(res), z1 -> p1
  gemm_bt<6><<<dim3(8, 64, 2), 256, 0, stream>>>(midb, bfc1, 8192, 1024, 4096,
                                                 out, nullptr, out, fc1b, p1);
  // 9: out += p1
  addp_kernel<<<8192, 256, 0, stream>>>(out, p1);
}

// Round 7
// 535.779 us; speedup vs baseline: 1.1487x; 1.0955x over previous
//
#include <hip/hip_runtime.h>
#include <math.h>

// ---------------------------------------------------------------------------
// VideoChat3 vision encoder block, bf16-MFMA pipeline. Round 7:
//  - REVERT split-K (both variants regressed; FC1 is latency-bound not
//    parallelism-bound: FC0 at 8 blk/CU sits at the same ~570 TF)
//  - XCD-affine grid swizzle on all GEMMs: bid%8 = XCD under round-robin;
//    give each XCD a bm-slab x all bn so per-k-slice working set fits its
//    private 4MB L2 (A-slice+B-slice ~128KB, 8x reuse each). Attacks the
//    global_load_lds latency that stalls the 2-barrier K-loop.
// S=8192, H=1024, NH=16, HD=64, NSEG=8, L=1024, MLP=4096.
// ---------------------------------------------------------------------------

typedef __bf16 bf16x8 __attribute__((ext_vector_type(8)));
typedef float f32x4 __attribute__((ext_vector_type(4)));
typedef float f32x16 __attribute__((ext_vector_type(16)));
typedef unsigned int u32;

__device__ __forceinline__ unsigned short f2b(float f) {  // RNE f32->bf16
  unsigned u = __float_as_uint(f);
  return (unsigned short)((u + 0x7FFFu + ((u >> 16) & 1u)) >> 16);
}
__device__ __forceinline__ float b2f(unsigned short h) {
  return __uint_as_float(((unsigned)h) << 16);
}
__device__ __forceinline__ void async_ld16(const void* g, void* l) {
  __builtin_amdgcn_global_load_lds((__attribute__((address_space(1))) void*)g,
                                   (__attribute__((address_space(3))) void*)l,
                                   16, 0, 0);
}
__device__ __forceinline__ float exp2fast(float x) {
#if __has_builtin(__builtin_amdgcn_exp2f)
  return __builtin_amdgcn_exp2f(x);
#else
  return exp2f(x);
#endif
}
__device__ __forceinline__ float rcpfast(float x) {
#if __has_builtin(__builtin_amdgcn_rcpf)
  return __builtin_amdgcn_rcpf(x);
#else
  return 1.0f / x;
#endif
}

// ---------------- fused: weight cast fp32->bf16  +  LN0 --------------------
__global__ __launch_bounds__(256) void castln_kernel(
    const float* __restrict__ w0, const float* __restrict__ w1,
    const float* __restrict__ w2, const float* __restrict__ w3,
    unsigned short* __restrict__ wdst,
    const float* __restrict__ x, const float* __restrict__ g,
    const float* __restrict__ bt, unsigned short* __restrict__ hout) {
  __shared__ float red[8];
  const int blk = blockIdx.x;
  if (blk < 12288) {
    const int t = blk * 256 + threadIdx.x;  // float4 groups
    const float* src;
    int off;
    if (t < 786432) { src = w0; off = t; }
    else if (t < 1048576) { src = w1; off = t - 786432; }
    else if (t < 2097152) { src = w2; off = t - 1048576; }
    else { src = w3; off = t - 2097152; }
    const float4 v = ((const float4*)src)[off];
    ushort4 o;
    o.x = f2b(v.x); o.y = f2b(v.y); o.z = f2b(v.z); o.w = f2b(v.w);
    ((ushort4*)wdst)[t] = o;
    return;
  }
  const int row = blk - 12288, t = threadIdx.x;
  const float4 v = ((const float4*)(x + (size_t)row * 1024))[t];
  float s = v.x + v.y + v.z + v.w;
  float s2 = v.x * v.x + v.y * v.y + v.z * v.z + v.w * v.w;
#pragma unroll
  for (int m = 1; m < 64; m <<= 1) {
    s += __shfl_xor(s, m, 64);
    s2 += __shfl_xor(s2, m, 64);
  }
  if ((t & 63) == 0) { red[t >> 6] = s; red[4 + (t >> 6)] = s2; }
  __syncthreads();
  const float ts = red[0] + red[1] + red[2] + red[3];
  const float ts2 = red[4] + red[5] + red[6] + red[7];
  const float mean = ts * (1.f / 1024.f);
  const float var = ts2 * (1.f / 1024.f) - mean * mean;
  const float inv = rsqrtf(var + 1e-5f);
  const float4 gv = ((const float4*)g)[t];
  const float4 bv = ((const float4*)bt)[t];
  ushort4 o;
  o.x = f2b((v.x - mean) * inv * gv.x + bv.x);
  o.y = f2b((v.y - mean) * inv * gv.y + bv.y);
  o.z = f2b((v.z - mean) * inv * gv.z + bv.z);
  o.w = f2b((v.w - mean) * inv * gv.w + bv.w);
  ((ushort4*)hout)[(size_t)row * 256 + t] = o;
}

// ---------------- layernorm (row of 1024) -> bf16 (standalone, LN1) --------
__global__ __launch_bounds__(256) void ln_kernel(const float* __restrict__ x,
                                                 const float* __restrict__ g,
                                                 const float* __restrict__ bt,
                                                 unsigned short* __restrict__ out) {
  __shared__ float red[8];
  const int row = blockIdx.x, t = threadIdx.x;
  const float4 v = ((const float4*)(x + (size_t)row * 1024))[t];
  float s = v.x + v.y + v.z + v.w;
  float s2 = v.x * v.x + v.y * v.y + v.z * v.z + v.w * v.w;
#pragma unroll
  for (int m = 1; m < 64; m <<= 1) {
    s += __shfl_xor(s, m, 64);
    s2 += __shfl_xor(s2, m, 64);
  }
  if ((t & 63) == 0) { red[t >> 6] = s; red[4 + (t >> 6)] = s2; }
  __syncthreads();
  const float ts = red[0] + red[1] + red[2] + red[3];
  const float ts2 = red[4] + red[5] + red[6] + red[7];
  const float mean = ts * (1.f / 1024.f);
  const float var = ts2 * (1.f / 1024.f) - mean * mean;
  const float inv = rsqrtf(var + 1e-5f);
  const float4 gv = ((const float4*)g)[t];
  const float4 bv = ((const float4*)bt)[t];
  ushort4 o;
  o.x = f2b((v.x - mean) * inv * gv.x + bv.x);
  o.y = f2b((v.y - mean) * inv * gv.y + bv.y);
  o.z = f2b((v.z - mean) * inv * gv.z + bv.z);
  o.w = f2b((v.w - mean) * inv * gv.w + bv.w);
  ((ushort4*)out)[(size_t)row * 256 + t] = o;
}

// ---------------- GEMM: C[M,N] = A[M,K] @ B[N,K]^T, bf16 in, fp32 acc ------
// 128x128 tile, 4 waves, 16x16x32 MFMA, XOR-swizzled LDS (conflict-free).
// 1D grid with XCD-affine swizzle: j=bid&7 (XCD under %8 round-robin),
// bm=(g/NBN)*8+j, bn=g%NBN -> each XCD works a bm-slab across all bn,
// k-slices of A and B stay resident in its private L2.
// MODE 1: outf = acc + res           MODE 2: outb = bf16(gelu(acc+bias))
// MODE 3: outf = acc + bias + res    MODE 4: outb = bf16(acc)
template <int MODE, int NBN>
__global__ __launch_bounds__(256) void gemm_bt(
    const unsigned short* __restrict__ A, const unsigned short* __restrict__ B,
    int M, int N, int K, float* __restrict__ outf, unsigned short* __restrict__ outb,
    const float* __restrict__ res, const float* __restrict__ bias) {
  __shared__ __align__(16) unsigned short As[128 * 32];
  __shared__ __align__(16) unsigned short Bs[128 * 32];
  const int bid = blockIdx.x;
  const int j8 = bid & 7, g = bid >> 3;
  const int bm = ((g / NBN) * 8 + j8) * 128;
  const int bn = (g % NBN) * 128;
  const int t = threadIdx.x, wave = t >> 6, lane = t & 63;
  const int quad = lane >> 4, l16 = lane & 15;
  const int wm = (wave >> 1) * 64, wn = (wave & 1) * 64;
  const int srow = lane >> 2;
  const int scol = (((lane & 3) ^ ((lane >> 3) & 3)) * 8);  // swizzled source col
  const unsigned short* Ag0 = A + (size_t)(bm + wave * 32 + srow) * K + scol;
  const unsigned short* Ag1 = Ag0 + (size_t)16 * K;
  const unsigned short* Bg0 = B + (size_t)(bn + wave * 32 + srow) * K + scol;
  const unsigned short* Bg1 = Bg0 + (size_t)16 * K;
  unsigned short* Al = As + wave * 1024;
  unsigned short* Bl = Bs + wave * 1024;
  const int swg = (l16 >> 1) & 3;  // read-side swizzle key
  f32x4 acc[4][4] = {};
  for (int k0 = 0; k0 < K; k0 += 32) {
    async_ld16(Ag0 + k0, Al);
    async_ld16(Ag1 + k0, Al + 512);
    async_ld16(Bg0 + k0, Bl);
    async_ld16(Bg1 + k0, Bl + 512);
    __syncthreads();
    bf16x8 af[4], bfv[4];
#pragma unroll
    for (int i = 0; i < 4; i++)
      af[i] = *(const bf16x8*)(As + (wm + i * 16 + l16) * 32 + (quad ^ swg) * 8);
#pragma unroll
    for (int jj = 0; jj < 4; jj++)
      bfv[jj] = *(const bf16x8*)(Bs + (wn + jj * 16 + l16) * 32 + (quad ^ swg) * 8);
#pragma unroll
    for (int i = 0; i < 4; i++)
#pragma unroll
      for (int jj = 0; jj < 4; jj++)
        acc[i][jj] = __builtin_amdgcn_mfma_f32_16x16x32_bf16(af[i], bfv[jj], acc[i][jj], 0, 0, 0);
    __syncthreads();
  }
#pragma unroll
  for (int i = 0; i < 4; i++)
#pragma unroll
    for (int jj = 0; jj < 4; jj++)
#pragma unroll
      for (int r = 0; r < 4; r++) {
        const int m = bm + wm + i * 16 + quad * 4 + r;
        const int n = bn + wn + jj * 16 + l16;
        const size_t idx = (size_t)m * N + n;
        const float v = acc[i][jj][r];
        if (MODE == 1) {
          outf[idx] = v + res[idx];
        } else if (MODE == 2) {
          // tanh-GELU via native exp2: g = z*t/(t+1), t = exp2(2.88539*u)
          const float z = v + bias[n];
          const float u = z * (0.7978845608f + 0.03567740814f * z * z);
          const float e = fminf(u * 2.885390082f, 80.f);
          const float tt = exp2fast(e);
          outb[idx] = f2b(z * tt * rcpfast(tt + 1.0f));
        } else if (MODE == 3) {
          outf[idx] = v + bias[n] + res[idx];
        } else {  // MODE 4
          outb[idx] = f2b(v);
        }
      }
}

// ---------------- fused RoPE + V-transpose ---------------------------------
__device__ __forceinline__ u32 rope2(u32 in, float c, float sn, float sc) {
  const float a = b2f((unsigned short)(in & 0xffff));
  const float b = b2f((unsigned short)(in >> 16));
  return (u32)f2b((a * c - b * sn) * sc) | ((u32)f2b((a * sn + b * c) * sc) << 16);
}
__global__ __launch_bounds__(256) void ropevt_kernel(const unsigned short* __restrict__ qkv,
                                                     const float* __restrict__ cb,
                                                     const float* __restrict__ sb,
                                                     unsigned short* __restrict__ qh,
                                                     unsigned short* __restrict__ kh,
                                                     unsigned short* __restrict__ vt) {
  __shared__ unsigned short tile[64][72];
  const int blk = blockIdx.x;
  if (blk < 4096) {
    const int tid = blk * 256 + threadIdx.x;  // S*NH*8 threads
    const int ii = tid & 7, head = (tid >> 3) & 15, s = tid >> 7;
    const float4 cv = *(const float4*)(cb + s * 32 + ii * 4);
    const float4 sv = *(const float4*)(sb + s * 32 + ii * 4);
    const unsigned short* base = qkv + (size_t)s * 3072 + head * 64 + ii * 8;
    const uint4 qa = *(const uint4*)base;
    const uint4 ka = *(const uint4*)(base + 1024);
    const int seg = s >> 10, l = s & 1023;
    const size_t o = ((size_t)((seg * 16 + head) * 1024 + l)) * 64 + ii * 8;
    const float QSC = 0.125f * 1.44269504f;
    uint4 qo, ko;
    qo.x = rope2(qa.x, cv.x, sv.x, QSC); ko.x = rope2(ka.x, cv.x, sv.x, 1.f);
    qo.y = rope2(qa.y, cv.y, sv.y, QSC); ko.y = rope2(ka.y, cv.y, sv.y, 1.f);
    qo.z = rope2(qa.z, cv.z, sv.z, QSC); ko.z = rope2(ka.z, cv.z, sv.z, 1.f);
    qo.w = rope2(qa.w, cv.w, sv.w, QSC); ko.w = rope2(ka.w, cv.w, sv.w, 1.f);
    *(uint4*)(qh + o) = qo;
    *(uint4*)(kh + o) = ko;
    return;
  }
  const int b = blk - 4096;  // 8*16*16
  const int lt = b & 15, head = (b >> 4) & 15, seg = b >> 8;
  const int t = threadIdx.x;
  const int r = t >> 2, c0 = (t & 3) * 16;
  const unsigned short* src =
      qkv + ((size_t)(seg * 1024 + lt * 64 + r)) * 3072 + 2048 + head * 64 + c0;
#pragma unroll
  for (int k = 0; k < 16; k++) tile[r][c0 + k] = src[k];
  __syncthreads();
  unsigned short* dst =
      vt + ((size_t)((seg * 16 + head) * 64 + r)) * 1024 + lt * 64 + c0;
#pragma unroll
  for (int k = 0; k < 16; k++) dst[k] = tile[c0 + k][r];
}

// ---------------- flash attention, 32x32x16 MFMA, in-register P ------------
__global__ __launch_bounds__(256) void attn_kernel(const unsigned short* __restrict__ qh,
                                                   const unsigned short* __restrict__ kh,
                                                   const unsigned short* __restrict__ vt,
                                                   unsigned short* __restrict__ out) {
  __shared__ __align__(16) unsigned short Qs[128 * 64];
  __shared__ __align__(16) unsigned short Ks[64 * 64];
  __shared__ __align__(16) unsigned short Vs[64 * 64];  // [hd][key]
  __shared__ float wl[128];
  const int b = blockIdx.x;
  const int head = b & 15, seg = (b >> 4) & 7, qt = b >> 7;
  const int t = threadIdx.x, wave = t >> 6, lane = t & 63;
  const int h = lane >> 5, q31 = lane & 31;
  const size_t sh = (size_t)(seg * 16 + head);
  const unsigned short* qbase = qh + (sh * 1024 + (size_t)qt * 128) * 64;
  const unsigned short* kbase = kh + sh * 1024 * 64;
  const unsigned short* vbase = vt + sh * 64 * 1024;
  const int r8 = lane >> 3;
  const int c8 = ((lane & 7) ^ (r8 & 7)) * 8;  // swizzled source col (shorts)
#pragma unroll
  for (int cc = 0; cc < 4; cc++) {  // stage Q once (16KB, 16 chunks)
    const int chunk = wave * 4 + cc;
    async_ld16(qbase + (size_t)(chunk * 8 + r8) * 64 + c8, Qs + chunk * 512);
  }
  const int qrow_l = wave * 32 + q31;          // this lane's query row in tile
  const int qsw = qrow_l & 7;                  // Qs swizzle key
  bf16x8 qf[4];                                // Q B-frags, loaded once
  float lsum = 0.f;
  f32x16 oacc[2] = {};

  for (int kt = 0; kt < 16; kt++) {
    const int ch0 = wave * 2;
    async_ld16(kbase + (size_t)(kt * 64 + ch0 * 8 + r8) * 64 + c8, Ks + ch0 * 512);
    async_ld16(kbase + (size_t)(kt * 64 + ch0 * 8 + 8 + r8) * 64 + c8, Ks + ch0 * 512 + 512);
    async_ld16(vbase + (size_t)(ch0 * 8 + r8) * 1024 + kt * 64 + c8, Vs + ch0 * 512);
    async_ld16(vbase + (size_t)(ch0 * 8 + 8 + r8) * 1024 + kt * 64 + c8, Vs + ch0 * 512 + 512);
    __syncthreads();
    if (kt == 0) {
#pragma unroll
      for (int ks = 0; ks < 4; ks++)
        qf[ks] = *(const bf16x8*)(Qs + qrow_l * 64 + (((2 * ks + h) ^ qsw)) * 8);
    }
    // S^T = K.Q^T : 2 key tiles x 4 ksteps
    f32x16 st[2] = {{}, {}};
#pragma unroll
    for (int T = 0; T < 2; T++) {
      const int krow = 32 * T + q31;
      const int ksw = krow & 7;
#pragma unroll
      for (int ks = 0; ks < 4; ks++) {
        const bf16x8 kf = *(const bf16x8*)(Ks + krow * 64 + (((2 * ks + h) ^ ksw)) * 8);
        st[T] = __builtin_amdgcn_mfma_f32_32x32x16_bf16(kf, qf[ks], st[T], 0, 0, 0);
      }
    }
    // p = exp2(s) (q pre-scaled by log2e/8); pack bf16 pairs per group
    u32 pk[2][4][2];
#pragma unroll
    for (int T = 0; T < 2; T++)
#pragma unroll
      for (int g = 0; g < 4; g++)
#pragma unroll
        for (int e = 0; e < 2; e++) {
          const float plo = exp2fast(st[T][4 * g + 2 * e]);
          const float phi = exp2fast(st[T][4 * g + 2 * e + 1]);
          lsum += plo + phi;
          pk[T][g][e] = (u32)f2b(plo) | ((u32)f2b(phi) << 16);
        }
    // half-wave exchange of the cross quads
    u32 rcv[2][4];
#pragma unroll
    for (int T = 0; T < 2; T++) {
      const u32 p0 = h ? pk[T][0][0] : pk[T][1][0];
      const u32 p1 = h ? pk[T][0][1] : pk[T][1][1];
      const u32 p2 = h ? pk[T][2][0] : pk[T][3][0];
      const u32 p3 = h ? pk[T][2][1] : pk[T][3][1];
      rcv[T][0] = (u32)__shfl_xor((int)p0, 32, 64);
      rcv[T][1] = (u32)__shfl_xor((int)p1, 32, 64);
      rcv[T][2] = (u32)__shfl_xor((int)p2, 32, 64);
      rcv[T][3] = (u32)__shfl_xor((int)p3, 32, 64);
    }
    // O += P.V
#pragma unroll
    for (int tt = 0; tt < 4; tt++) {
      const int T = tt >> 1, uu = tt & 1;
      union { u32 u[4]; bf16x8 v; } af;
      if (h == 0) {
        af.u[0] = pk[T][2 * uu][0];
        af.u[1] = pk[T][2 * uu][1];
        af.u[2] = rcv[T][2 * uu];
        af.u[3] = rcv[T][2 * uu + 1];
      } else {
        af.u[0] = rcv[T][2 * uu];
        af.u[1] = rcv[T][2 * uu + 1];
        af.u[2] = pk[T][2 * uu + 1][0];
        af.u[3] = pk[T][2 * uu + 1][1];
      }
#pragma unroll
      for (int ot = 0; ot < 2; ot++) {
        const int vrow = 32 * ot + q31;
        const int vsw = vrow & 7;
        const bf16x8 bv = *(const bf16x8*)(Vs + vrow * 64 + (((2 * tt + h) ^ vsw)) * 8);
        oacc[ot] = __builtin_amdgcn_mfma_f32_32x32x16_bf16(af.v, bv, oacc[ot], 0, 0, 0);
      }
    }
    __syncthreads();
  }
  // epilogue: full row-sum, normalize, store
  lsum += __shfl_xor(lsum, 32, 64);
  if (h == 0) wl[wave * 32 + q31] = lsum;
  const int qglob = seg * 1024 + qt * 128 + wave * 32;
#pragma unroll
  for (int g = 0; g < 4; g++) {
    const float4 lv = *(const float4*)&wl[wave * 32 + 8 * g + 4 * h];
#pragma unroll
    for (int m = 0; m < 4; m++) {
      const int r16 = 4 * g + m;
      const int qrow = qglob + m + 8 * g + 4 * h;
      const float invl = rcpfast((&lv.x)[m]);
#pragma unroll
      for (int ot = 0; ot < 2; ot++)
        out[(size_t)qrow * 1024 + head * 64 + 32 * ot + q31] = f2b(oacc[ot][r16] * invl);
    }
  }
}

// ---------------------------------------------------------------------------
extern "C" void kernel_launch(void* const* d_in, const int* in_sizes, int n_in,
                              void* d_out, int out_size, void* d_ws, size_t ws_size,
                              hipStream_t stream) {
  (void)in_sizes; (void)n_in; (void)out_size; (void)ws_size;
  const float* x    = (const float*)d_in[0];
  const float* wqkv = (const float*)d_in[1];
  const float* wo   = (const float*)d_in[2];
  const float* ln0g = (const float*)d_in[3];
  const float* ln0b = (const float*)d_in[4];
  const float* ln1g = (const float*)d_in[5];
  const float* ln1b = (const float*)d_in[6];
  const float* fc0w = (const float*)d_in[7];
  const float* fc0b = (const float*)d_in[8];
  const float* fc1w = (const float*)d_in[9];
  const float* fc1b = (const float*)d_in[10];
  const float* rc   = (const float*)d_in[11];
  const float* rsn  = (const float*)d_in[12];
  float* out = (float*)d_out;
  char* w = (char*)d_ws;
  const size_t MB = 1u << 20;
  unsigned short* hb    = (unsigned short*)(w + 0);
  unsigned short* bqkv  = (unsigned short*)(w + 16 * MB);
  unsigned short* bwo   = (unsigned short*)(w + 22 * MB);
  unsigned short* bfc0  = (unsigned short*)(w + 24 * MB);
  unsigned short* bfc1  = (unsigned short*)(w + 32 * MB);
  unsigned short* qhb   = (unsigned short*)(w + 40 * MB);
  unsigned short* khb   = (unsigned short*)(w + 56 * MB);
  unsigned short* vtb   = (unsigned short*)(w + 72 * MB);
  unsigned short* attnb = (unsigned short*)(w + 88 * MB);
  unsigned short* qkvb  = (unsigned short*)(w + 104 * MB);
  unsigned short* midb  = (unsigned short*)(w + 104 * MB);  // alias, qkvb dead

  // 1: weight casts + LN0 (one dispatch)
  castln_kernel<<<20480, 256, 0, stream>>>(wqkv, wo, fc0w, fc1w, bqkv,
                                           x, ln0g, ln0b, hb);
  // 2: QKV = hb @ wqkv^T        (grid 24x64, XCD-swizzled 1D)
  gemm_bt<4, 24><<<1536, 256, 0, stream>>>(hb, bqkv, 8192, 3072, 1024,
                                           nullptr, qkvb, nullptr, nullptr);
  // 3: RoPE + V-transpose (one dispatch)
  ropevt_kernel<<<6144, 256, 0, stream>>>(qkvb, rc, rsn, qhb, khb, vtb);
  // 4: attention
  attn_kernel<<<1024, 256, 0, stream>>>(qhb, khb, vtb, attnb);
  // 5: WO: out = attn @ wo^T + x  (grid 8x64)
  gemm_bt<1, 8><<<512, 256, 0, stream>>>(attnb, bwo, 8192, 1024, 1024,
                                         out, nullptr, x, nullptr);
  // 6: LN1
  ln_kernel<<<8192, 256, 0, stream>>>(out, ln1g, ln1b, hb);
  // 7: FC0 (+bias, GELU) -> midb  (grid 32x64)
  gemm_bt<2, 32><<<2048, 256, 0, stream>>>(hb, bfc0, 8192, 4096, 1024,
                                           nullptr, midb, nullptr, fc0b);
  // 8: FC1: out = mid @ fc1^T + bias + out  (grid 8x64)
  gemm_bt<3, 8><<<512, 256, 0, stream>>>(midb, bfc1, 8192, 1024, 4096,
                                         out, nullptr, out, fc1b);
}